// Round 1
// baseline (301.619 us; speedup 1.0000x reference)
//
#include <hip/hip_runtime.h>
#include <hip/hip_bf16.h>

typedef float f32x4 __attribute__((ext_vector_type(4)));
typedef __bf16 bf16x8 __attribute__((ext_vector_type(8)));
typedef unsigned short u16x8 __attribute__((ext_vector_type(8)));

#define NB 4
#define SL 2048
#define NH 16
#define HD 64
#define QBLK 64
#define KBLK 64
#define PAD 72

static __device__ __forceinline__ unsigned short f2bf(float f) {
    unsigned u = __builtin_bit_cast(unsigned, f);
    u += 0x7fffu + ((u >> 16) & 1u);   // round-to-nearest-even
    return (unsigned short)(u >> 16);
}

__global__ __launch_bounds__(256, 2)
void fattn_kernel(const float* __restrict__ Qg, const float* __restrict__ Kg,
                  const float* __restrict__ Vg, float* __restrict__ Og)
{
    __shared__ unsigned short Klds[KBLK * PAD];      // K tile, row-major [s][e]
    __shared__ unsigned short Vt[HD * PAD];          // V tile, transposed [d][s]
    __shared__ unsigned short Plds[4 * 16 * PAD];    // per-wave P tile [q][s]

    const int tid  = threadIdx.x;
    const int w    = tid >> 6;
    const int lane = tid & 63;
    const int g    = lane >> 4;
    const int li   = lane & 15;

    const int id = blockIdx.x;
    const int qt = id & (SL / QBLK - 1);
    const int bh = id >> 5;
    const int b  = bh >> 4;
    const int h  = bh & (NH - 1);

    const int qb = qt * QBLK;
    const int qw = qb + w * 16;

    // ---- load Q fragments for this wave's 16 rows, pre-scaled by 1/sqrt(64) ----
    bf16x8 qfrag[2];
    {
        const int q = qw + li;
        const float* qp = Qg + ((size_t)(b * SL + q) * NH + h) * HD + g * 8;
        #pragma unroll
        for (int f = 0; f < 2; ++f) {
            u16x8 t;
            #pragma unroll
            for (int j = 0; j < 8; ++j) t[j] = f2bf(qp[f * 32 + j] * 0.125f);
            qfrag[f] = __builtin_bit_cast(bf16x8, t);
        }
    }

    float m_run[4], l_run[4];
    f32x4 oacc[4];
    #pragma unroll
    for (int r = 0; r < 4; ++r) { m_run[r] = -1e30f; l_run[r] = 0.f; }
    #pragma unroll
    for (int dsub = 0; dsub < 4; ++dsub) oacc[dsub] = f32x4{0.f, 0.f, 0.f, 0.f};

    for (int t = 0; t <= qt; ++t) {
        const int s0 = t * KBLK;
        __syncthreads();   // previous tile's reads done before restage
        // ---- stage K (row-major bf16) and V (transposed bf16) ----
        {
            const int s  = tid >> 2;
            const int c0 = (tid & 3) * 16;
            const float* kp = Kg + ((size_t)(b * SL + s0 + s) * NH + h) * HD + c0;
            const float* vp = Vg + ((size_t)(b * SL + s0 + s) * NH + h) * HD + c0;
            u16x8 k0, k1;
            unsigned short vb[16];
            #pragma unroll
            for (int j = 0; j < 8; ++j) { k0[j] = f2bf(kp[j]); k1[j] = f2bf(kp[8 + j]); }
            #pragma unroll
            for (int j = 0; j < 16; ++j) vb[j] = f2bf(vp[j]);
            *(u16x8*)&Klds[s * PAD + c0]     = k0;
            *(u16x8*)&Klds[s * PAD + c0 + 8] = k1;
            #pragma unroll
            for (int j = 0; j < 16; ++j) Vt[(c0 + j) * PAD + s] = vb[j];
        }
        __syncthreads();

        // ---- S = (Q/8) K^T over 4 s-subtiles of 16 ----
        f32x4 sacc[4];
        #pragma unroll
        for (int sub = 0; sub < 4; ++sub) {
            bf16x8 kf0 = __builtin_bit_cast(bf16x8, *(u16x8*)&Klds[(sub * 16 + li) * PAD + g * 8]);
            bf16x8 kf1 = __builtin_bit_cast(bf16x8, *(u16x8*)&Klds[(sub * 16 + li) * PAD + 32 + g * 8]);
            f32x4 c = f32x4{0.f, 0.f, 0.f, 0.f};
            c = __builtin_amdgcn_mfma_f32_16x16x32_bf16(qfrag[0], kf0, c, 0, 0, 0);
            c = __builtin_amdgcn_mfma_f32_16x16x32_bf16(qfrag[1], kf1, c, 0, 0, 0);
            sacc[sub] = c;
        }

        // ---- causal mask (diagonal tile only) ----
        if (t == qt) {
            #pragma unroll
            for (int sub = 0; sub < 4; ++sub)
                #pragma unroll
                for (int r = 0; r < 4; ++r) {
                    const int s = s0 + sub * 16 + li;
                    const int q = qw + g * 4 + r;
                    if (s > q) sacc[sub][r] = -1e30f;
                }
        }

        // ---- online softmax (rows live in 16-lane groups) ----
        float tmax[4];
        #pragma unroll
        for (int r = 0; r < 4; ++r)
            tmax[r] = fmaxf(fmaxf(sacc[0][r], sacc[1][r]), fmaxf(sacc[2][r], sacc[3][r]));
        #pragma unroll
        for (int r = 0; r < 4; ++r) {
            #pragma unroll
            for (int msk = 1; msk < 16; msk <<= 1)
                tmax[r] = fmaxf(tmax[r], __shfl_xor(tmax[r], msk));
        }
        float alpha[4], rsum[4];
        unsigned short pb[4][4];
        #pragma unroll
        for (int r = 0; r < 4; ++r) {
            const float mnew = fmaxf(m_run[r], tmax[r]);
            alpha[r] = __expf(m_run[r] - mnew);
            m_run[r] = mnew;
            rsum[r]  = 0.f;
        }
        #pragma unroll
        for (int sub = 0; sub < 4; ++sub)
            #pragma unroll
            for (int r = 0; r < 4; ++r) {
                const float p = __expf(sacc[sub][r] - m_run[r]);
                rsum[r] += p;
                pb[sub][r] = f2bf(p);
            }
        #pragma unroll
        for (int r = 0; r < 4; ++r) {
            #pragma unroll
            for (int msk = 1; msk < 16; msk <<= 1)
                rsum[r] += __shfl_xor(rsum[r], msk);
            l_run[r] = l_run[r] * alpha[r] + rsum[r];
        }
        #pragma unroll
        for (int dsub = 0; dsub < 4; ++dsub)
            #pragma unroll
            for (int r = 0; r < 4; ++r) oacc[dsub][r] *= alpha[r];

        // ---- P -> wave-private LDS (bf16), then refragment as MFMA A ----
        unsigned short* pw = &Plds[w * 16 * PAD];
        #pragma unroll
        for (int sub = 0; sub < 4; ++sub)
            #pragma unroll
            for (int r = 0; r < 4; ++r)
                pw[(g * 4 + r) * PAD + sub * 16 + li] = pb[sub][r];

        bf16x8 pf0 = __builtin_bit_cast(bf16x8, *(u16x8*)&pw[li * PAD + g * 8]);
        bf16x8 pf1 = __builtin_bit_cast(bf16x8, *(u16x8*)&pw[li * PAD + 32 + g * 8]);
        #pragma unroll
        for (int dsub = 0; dsub < 4; ++dsub) {
            bf16x8 vf0 = __builtin_bit_cast(bf16x8, *(u16x8*)&Vt[(dsub * 16 + li) * PAD + g * 8]);
            bf16x8 vf1 = __builtin_bit_cast(bf16x8, *(u16x8*)&Vt[(dsub * 16 + li) * PAD + 32 + g * 8]);
            oacc[dsub] = __builtin_amdgcn_mfma_f32_16x16x32_bf16(pf0, vf0, oacc[dsub], 0, 0, 0);
            oacc[dsub] = __builtin_amdgcn_mfma_f32_16x16x32_bf16(pf1, vf1, oacc[dsub], 0, 0, 0);
        }
    }

    // ---- epilogue: O = acc / l ----
    #pragma unroll
    for (int r = 0; r < 4; ++r) {
        const int q = qw + g * 4 + r;
        const float inv = 1.0f / l_run[r];
        float* op = Og + ((size_t)(b * SL + q) * NH + h) * HD + li;
        #pragma unroll
        for (int dsub = 0; dsub < 4; ++dsub)
            op[dsub * 16] = oacc[dsub][r] * inv;
    }
}

extern "C" void kernel_launch(void* const* d_in, const int* in_sizes, int n_in,
                              void* d_out, int out_size, void* d_ws, size_t ws_size,
                              hipStream_t stream) {
    const float* Qg = (const float*)d_in[0];
    const float* Kg = (const float*)d_in[1];
    const float* Vg = (const float*)d_in[2];
    float* Og = (float*)d_out;
    dim3 grid(NB * NH * (SL / QBLK));
    dim3 block(256);
    hipLaunchKernelGGL(fattn_kernel, grid, block, 0, stream, Qg, Kg, Vg, Og);
}

// Round 2
// 228.371 us; speedup vs baseline: 1.3207x; 1.3207x over previous
//
#include <hip/hip_runtime.h>
#include <hip/hip_bf16.h>

typedef float f32x4 __attribute__((ext_vector_type(4)));
typedef __bf16 bf16x8 __attribute__((ext_vector_type(8)));
typedef unsigned short u16x8 __attribute__((ext_vector_type(8)));
typedef unsigned short u16x4 __attribute__((ext_vector_type(4)));

#define NB 4
#define SL 2048
#define NH 16
#define HD 64
#define QBLK 128
#define KBLK 64
#define PAD 72

static __device__ __forceinline__ unsigned short f2bf(float f) {
    unsigned u = __builtin_bit_cast(unsigned, f);
    u += 0x7fffu + ((u >> 16) & 1u);   // round-to-nearest-even
    return (unsigned short)(u >> 16);
}

// ---- prologue 1: K fp32 [b][s][h][e] -> bf16 [b][h][s][e] ----
__global__ void conv_k(const float* __restrict__ Kg, unsigned short* __restrict__ Kb) {
    const int idx = (blockIdx.x * 256 + threadIdx.x) * 4;
    const int e    = idx & 63;
    const int rest = idx >> 6;          // (b*SL+s)*NH + h
    const int h    = rest & 15;
    const int bs   = rest >> 4;         // b*SL + s
    const int b    = bs >> 11;
    const int s    = bs & (SL - 1);
    f32x4 v = *(const f32x4*)(Kg + idx);
    u16x4 o;
    #pragma unroll
    for (int j = 0; j < 4; ++j) o[j] = f2bf(v[j]);
    *(u16x4*)(Kb + (((size_t)(b * NH + h) * SL + s) * HD + e)) = o;
}

// ---- prologue 2: V fp32 [b][s][h][d] -> bf16 transposed [b][h][d][s] ----
__global__ void conv_v(const float* __restrict__ Vg, unsigned short* __restrict__ Vtb) {
    __shared__ unsigned short T[64 * PAD];
    const int tid = threadIdx.x;
    const int id  = blockIdx.x;         // bh*32 + s_tile
    const int st  = id & 31;
    const int bh  = id >> 5;
    const int s0  = st * 64;
    {
        const int sl = tid >> 2, c = (tid & 3) * 16;
        const float* src = Vg + ((size_t)((bh >> 4) * SL + s0 + sl) * NH + (bh & 15)) * HD + c;
        u16x8 a, b2;
        #pragma unroll
        for (int j = 0; j < 8; ++j) { a[j] = f2bf(src[j]); b2[j] = f2bf(src[8 + j]); }
        *(u16x8*)&T[sl * PAD + c]     = a;
        *(u16x8*)&T[sl * PAD + c + 8] = b2;
    }
    __syncthreads();
    {
        const int d = tid >> 2, sc = (tid & 3) * 16;
        u16x8 o0, o1;
        #pragma unroll
        for (int j = 0; j < 8; ++j) { o0[j] = T[(sc + j) * PAD + d]; o1[j] = T[(sc + 8 + j) * PAD + d]; }
        unsigned short* dst = Vtb + ((size_t)bh * HD + d) * SL + s0 + sc;
        *(u16x8*)dst       = o0;
        *(u16x8*)(dst + 8) = o1;
    }
}

// ---- main flash-attention kernel ----
__global__ __launch_bounds__(256, 2)
void fattn_kernel(const float* __restrict__ Qg, const unsigned short* __restrict__ Kb,
                  const unsigned short* __restrict__ Vtb, float* __restrict__ Og)
{
    __shared__ unsigned short Klds[KBLK * PAD];       // K tile [s][e]
    __shared__ unsigned short Vlds[HD * PAD];         // V tile transposed [d][s]
    __shared__ unsigned short Plds[4 * 32 * PAD];     // per-wave P [q][s]

    const int tid  = threadIdx.x;
    const int w    = tid >> 6;
    const int lane = tid & 63;
    const int g    = lane >> 4;
    const int li   = lane & 15;

    const int qt = blockIdx.x & (SL / QBLK - 1);
    const int bh = blockIdx.x >> 4;
    const int b  = bh >> 4;
    const int h  = bh & (NH - 1);

    const int qb = qt * QBLK;
    const int qw = qb + w * 32;

    // Q fragments (2 per wave), pre-scaled by 1/sqrt(64)
    bf16x8 qfrag[2][2];
    #pragma unroll
    for (int f = 0; f < 2; ++f) {
        const int q = qw + f * 16 + li;
        const float* qp = Qg + ((size_t)(b * SL + q) * NH + h) * HD;
        #pragma unroll
        for (int c = 0; c < 2; ++c) {
            u16x8 t;
            #pragma unroll
            for (int j = 0; j < 8; ++j) t[j] = f2bf(qp[c * 32 + g * 8 + j] * 0.125f);
            qfrag[f][c] = __builtin_bit_cast(bf16x8, t);
        }
    }

    float m_run[2][4], l_run[2][4];
    f32x4 oacc[2][4];
    #pragma unroll
    for (int f = 0; f < 2; ++f)
        #pragma unroll
        for (int r = 0; r < 4; ++r) { m_run[f][r] = -1e30f; l_run[f][r] = 0.f; }
    #pragma unroll
    for (int f = 0; f < 2; ++f)
        #pragma unroll
        for (int d = 0; d < 4; ++d) oacc[f][d] = f32x4{0.f, 0.f, 0.f, 0.f};

    const int srow = tid >> 2;
    const int scol = (tid & 3) * 16;
    const int tlast = 2 * qt + 1;

    for (int t = 0; t <= tlast; ++t) {
        const int s0 = t * KBLK;
        __syncthreads();
        // ---- stage K and V^T tiles (pure bf16 copies) ----
        {
            const u16x8* ksrc = (const u16x8*)(Kb + ((size_t)bh * SL + s0) * HD);
            u16x8 k0 = ksrc[tid * 2], k1 = ksrc[tid * 2 + 1];
            const u16x8* vsrc = (const u16x8*)(Vtb + ((size_t)bh * HD + srow) * SL + s0 + scol);
            u16x8 v0 = vsrc[0], v1 = vsrc[1];
            *(u16x8*)&Klds[srow * PAD + scol]     = k0;
            *(u16x8*)&Klds[srow * PAD + scol + 8] = k1;
            *(u16x8*)&Vlds[srow * PAD + scol]     = v0;
            *(u16x8*)&Vlds[srow * PAD + scol + 8] = v1;
        }
        __syncthreads();

        // ---- S = (Q*scale) K^T ----
        f32x4 sacc[2][4];
        #pragma unroll
        for (int sub = 0; sub < 4; ++sub) {
            bf16x8 kf0 = __builtin_bit_cast(bf16x8, *(u16x8*)&Klds[(sub * 16 + li) * PAD + g * 8]);
            bf16x8 kf1 = __builtin_bit_cast(bf16x8, *(u16x8*)&Klds[(sub * 16 + li) * PAD + 32 + g * 8]);
            #pragma unroll
            for (int f = 0; f < 2; ++f) {
                f32x4 c = f32x4{0.f, 0.f, 0.f, 0.f};
                c = __builtin_amdgcn_mfma_f32_16x16x32_bf16(qfrag[f][0], kf0, c, 0, 0, 0);
                c = __builtin_amdgcn_mfma_f32_16x16x32_bf16(qfrag[f][1], kf1, c, 0, 0, 0);
                sacc[f][sub] = c;
            }
        }

        // ---- per-fragment mask + online softmax + P store ----
        #pragma unroll
        for (int f = 0; f < 2; ++f) {
            const int qf = qw + f * 16;
            if (s0 + KBLK - 1 > qf) {
                #pragma unroll
                for (int sub = 0; sub < 4; ++sub)
                    #pragma unroll
                    for (int r = 0; r < 4; ++r) {
                        const int s = s0 + sub * 16 + li;
                        const int q = qf + g * 4 + r;
                        if (s > q) sacc[f][sub][r] = -1e30f;
                    }
            }
            float tmax[4];
            #pragma unroll
            for (int r = 0; r < 4; ++r)
                tmax[r] = fmaxf(fmaxf(sacc[f][0][r], sacc[f][1][r]),
                                fmaxf(sacc[f][2][r], sacc[f][3][r]));
            #pragma unroll
            for (int r = 0; r < 4; ++r)
                #pragma unroll
                for (int msk = 1; msk < 16; msk <<= 1)
                    tmax[r] = fmaxf(tmax[r], __shfl_xor(tmax[r], msk));
            float alpha[4], rsum[4];
            unsigned short pb[4][4];
            #pragma unroll
            for (int r = 0; r < 4; ++r) {
                const float mnew = fmaxf(m_run[f][r], tmax[r]);
                alpha[r] = __expf(m_run[f][r] - mnew);
                m_run[f][r] = mnew;
                rsum[r] = 0.f;
            }
            #pragma unroll
            for (int sub = 0; sub < 4; ++sub)
                #pragma unroll
                for (int r = 0; r < 4; ++r) {
                    const float p = __expf(sacc[f][sub][r] - m_run[f][r]);
                    rsum[r] += p;
                    pb[sub][r] = f2bf(p);
                }
            #pragma unroll
            for (int r = 0; r < 4; ++r) {
                #pragma unroll
                for (int msk = 1; msk < 16; msk <<= 1)
                    rsum[r] += __shfl_xor(rsum[r], msk);
                l_run[f][r] = l_run[f][r] * alpha[r] + rsum[r];
            }
            #pragma unroll
            for (int d = 0; d < 4; ++d)
                #pragma unroll
                for (int r = 0; r < 4; ++r) oacc[f][d][r] *= alpha[r];
            unsigned short* pw = &Plds[(w * 32 + f * 16) * PAD];
            #pragma unroll
            for (int sub = 0; sub < 4; ++sub)
                #pragma unroll
                for (int r = 0; r < 4; ++r)
                    pw[(g * 4 + r) * PAD + sub * 16 + li] = pb[sub][r];
        }

        // ---- PV ----
        bf16x8 pf[2][2];
        #pragma unroll
        for (int f = 0; f < 2; ++f) {
            pf[f][0] = __builtin_bit_cast(bf16x8, *(u16x8*)&Plds[(w * 32 + f * 16 + li) * PAD + g * 8]);
            pf[f][1] = __builtin_bit_cast(bf16x8, *(u16x8*)&Plds[(w * 32 + f * 16 + li) * PAD + 32 + g * 8]);
        }
        #pragma unroll
        for (int d = 0; d < 4; ++d) {
            bf16x8 vf0 = __builtin_bit_cast(bf16x8, *(u16x8*)&Vlds[(d * 16 + li) * PAD + g * 8]);
            bf16x8 vf1 = __builtin_bit_cast(bf16x8, *(u16x8*)&Vlds[(d * 16 + li) * PAD + 32 + g * 8]);
            #pragma unroll
            for (int f = 0; f < 2; ++f) {
                oacc[f][d] = __builtin_amdgcn_mfma_f32_16x16x32_bf16(pf[f][0], vf0, oacc[f][d], 0, 0, 0);
                oacc[f][d] = __builtin_amdgcn_mfma_f32_16x16x32_bf16(pf[f][1], vf1, oacc[f][d], 0, 0, 0);
            }
        }
    }

    // ---- epilogue ----
    #pragma unroll
    for (int f = 0; f < 2; ++f)
        #pragma unroll
        for (int r = 0; r < 4; ++r) {
            const int q = qw + f * 16 + g * 4 + r;
            const float inv = 1.0f / l_run[f][r];
            float* op = Og + ((size_t)(b * SL + q) * NH + h) * HD + li;
            #pragma unroll
            for (int d = 0; d < 4; ++d)
                op[d * 16] = oacc[f][d][r] * inv;
        }
}

extern "C" void kernel_launch(void* const* d_in, const int* in_sizes, int n_in,
                              void* d_out, int out_size, void* d_ws, size_t ws_size,
                              hipStream_t stream) {
    const float* Qg = (const float*)d_in[0];
    const float* Kg = (const float*)d_in[1];
    const float* Vg = (const float*)d_in[2];
    float* Og = (float*)d_out;

    const size_t elems = (size_t)NB * NH * SL * HD;   // 8,388,608
    if (ws_size < 2 * elems * sizeof(unsigned short)) return;  // need 32 MB scratch
    unsigned short* Kb  = (unsigned short*)d_ws;
    unsigned short* Vtb = Kb + elems;

    hipLaunchKernelGGL(conv_k, dim3(elems / 4 / 256), dim3(256), 0, stream, Kg, Kb);
    hipLaunchKernelGGL(conv_v, dim3(NB * NH * (SL / 64)), dim3(256), 0, stream, Vg, Vtb);
    hipLaunchKernelGGL(fattn_kernel, dim3(NB * NH * (SL / QBLK)), dim3(256), 0, stream,
                       Qg, Kb, Vtb, Og);
}

// Round 3
// 166.854 us; speedup vs baseline: 1.8077x; 1.3687x over previous
//
#include <hip/hip_runtime.h>
#include <hip/hip_bf16.h>

typedef float f32x4 __attribute__((ext_vector_type(4)));
typedef __bf16 bf16x8 __attribute__((ext_vector_type(8)));
typedef unsigned short u16x8 __attribute__((ext_vector_type(8)));
typedef unsigned short u16x4 __attribute__((ext_vector_type(4)));

#define NB 4
#define SL 2048
#define NH 16
#define HD 64
#define QBLK 128
#define KBLK 64
#define PAD 72
#define NT (SL / QBLK)   // 16 q-tiles

static __device__ __forceinline__ unsigned short f2bf(float f) {
    unsigned u = __builtin_bit_cast(unsigned, f);
    u += 0x7fffu + ((u >> 16) & 1u);   // round-to-nearest-even
    return (unsigned short)(u >> 16);
}

// ---- prologue 1: K fp32 [b][s][h][e] -> bf16 [b][h][s][e] ----
__global__ void conv_k(const float* __restrict__ Kg, unsigned short* __restrict__ Kb) {
    const int idx = (blockIdx.x * 256 + threadIdx.x) * 4;
    const int e    = idx & 63;
    const int rest = idx >> 6;
    const int h    = rest & 15;
    const int bs   = rest >> 4;
    const int b    = bs >> 11;
    const int s    = bs & (SL - 1);
    f32x4 v = *(const f32x4*)(Kg + idx);
    u16x4 o;
    #pragma unroll
    for (int j = 0; j < 4; ++j) o[j] = f2bf(v[j]);
    *(u16x4*)(Kb + (((size_t)(b * NH + h) * SL + s) * HD + e)) = o;
}

// ---- prologue 2: V fp32 [b][s][h][d] -> bf16 transposed [b][h][d][s] ----
__global__ void conv_v(const float* __restrict__ Vg, unsigned short* __restrict__ Vtb) {
    __shared__ unsigned short T[64 * PAD];
    const int tid = threadIdx.x;
    const int id  = blockIdx.x;
    const int st  = id & 31;
    const int bh  = id >> 5;
    const int s0  = st * 64;
    {
        const int sl = tid >> 2, c = (tid & 3) * 16;
        const float* src = Vg + ((size_t)((bh >> 4) * SL + s0 + sl) * NH + (bh & 15)) * HD + c;
        u16x8 a, b2;
        #pragma unroll
        for (int j = 0; j < 8; ++j) { a[j] = f2bf(src[j]); b2[j] = f2bf(src[8 + j]); }
        *(u16x8*)&T[sl * PAD + c]     = a;
        *(u16x8*)&T[sl * PAD + c + 8] = b2;
    }
    __syncthreads();
    {
        const int d = tid >> 2, sc = (tid & 3) * 16;
        u16x8 o0, o1;
        #pragma unroll
        for (int j = 0; j < 8; ++j) { o0[j] = T[(sc + j) * PAD + d]; o1[j] = T[(sc + 8 + j) * PAD + d]; }
        unsigned short* dst = Vtb + ((size_t)bh * HD + d) * SL + s0 + sc;
        *(u16x8*)dst       = o0;
        *(u16x8*)(dst + 8) = o1;
    }
}

// ---- main flash-attention kernel: paired causal q-tiles (p, NT-1-p) ----
__global__ __launch_bounds__(512, 4)
void fattn_kernel(const float* __restrict__ Qg, const unsigned short* __restrict__ Kb,
                  const unsigned short* __restrict__ Vtb, float* __restrict__ Og)
{
    __shared__ unsigned short Klds[KBLK * PAD];      // K tile [s][e]
    __shared__ unsigned short Vlds[HD * PAD];        // V tile transposed [d][s]
    __shared__ unsigned short Plds[8 * 32 * PAD];    // 8 waves x 2 frags x 16 rows

    const int tid  = threadIdx.x;
    const int w    = tid >> 6;
    const int lane = tid & 63;
    const int g    = lane >> 4;
    const int li   = lane & 15;

    // blockIdx = rawp*64 + bh : same-bh blocks land on one XCD (L2 reuse);
    // rawp -> p so CU-cohabiting pairs (p, 7-p) have uniform total staging.
    const int bh   = blockIdx.x & 63;
    const int rawp = blockIdx.x >> 6;
    const int p    = (rawp < 4) ? rawp : 11 - rawp;
    const int b    = bh >> 4;
    const int h    = bh & 15;

    const int qrow0 = p * QBLK + w * 16;              // tile A (short)
    const int qrow1 = (NT - 1 - p) * QBLK + w * 16;   // tile B (long)
    const int tmax  = 2 * (NT - 1 - p) + 1;           // inclusive KV-tile bound

    // ---- Q fragments (pre-scaled by 1/8), vectorized fp32 loads ----
    bf16x8 qfrag[2][2];
    #pragma unroll 2
    for (int fi = 0; fi < 2; ++fi) {
        const int q = (fi == 0 ? qrow0 : qrow1) + li;
        const float* qp = Qg + ((size_t)(b * SL + q) * NH + h) * HD + g * 8;
        #pragma unroll
        for (int c = 0; c < 2; ++c) {
            f32x4 a = *(const f32x4*)(qp + c * 32);
            f32x4 b2 = *(const f32x4*)(qp + c * 32 + 4);
            u16x8 t;
            #pragma unroll
            for (int j = 0; j < 4; ++j) { t[j] = f2bf(a[j] * 0.125f); t[4 + j] = f2bf(b2[j] * 0.125f); }
            qfrag[fi][c] = __builtin_bit_cast(bf16x8, t);
        }
    }

    float m_run[2][4], l_run[2][4];
    f32x4 oacc[2][4];
    #pragma unroll
    for (int fi = 0; fi < 2; ++fi)
        #pragma unroll
        for (int r = 0; r < 4; ++r) { m_run[fi][r] = -1e30f; l_run[fi][r] = 0.f; }
    #pragma unroll
    for (int fi = 0; fi < 2; ++fi)
        #pragma unroll
        for (int d = 0; d < 4; ++d) oacc[fi][d] = f32x4{0.f, 0.f, 0.f, 0.f};

    const int srow = tid >> 3;           // 0..63
    const int scol = (tid & 7) * 8;      // 0..56
    const unsigned short* kbase = Kb  + (size_t)bh * SL * HD;
    const unsigned short* vbase = Vtb + (size_t)bh * HD * SL;

    // prefetch tile 0
    u16x8 kreg = *(const u16x8*)(kbase + (size_t)srow * HD + scol);
    u16x8 vreg = *(const u16x8*)(vbase + (size_t)srow * SL + scol);

    for (int t = 0; t <= tmax; ++t) {
        const int s0 = t * KBLK;
        __syncthreads();                               // readers of t-1 done
        *(u16x8*)&Klds[srow * PAD + scol] = kreg;
        *(u16x8*)&Vlds[srow * PAD + scol] = vreg;
        if (t < tmax) {                                // prefetch t+1 under compute of t
            const int s1 = s0 + KBLK;
            kreg = *(const u16x8*)(kbase + ((size_t)(s1 + srow)) * HD + scol);
            vreg = *(const u16x8*)(vbase + (size_t)srow * SL + s1 + scol);
        }
        __syncthreads();

        const bool act0 = (s0 <= qrow0 + 15);          // wave's A-frag has unmasked cols

        #pragma unroll 2
        for (int fi = 0; fi < 2; ++fi) {
            if (fi == 0 && !act0) continue;
            const int qf = (fi == 0) ? qrow0 : qrow1;

            // ---- S = (Q*scale) K^T ----
            f32x4 sacc[4];
            #pragma unroll
            for (int sub = 0; sub < 4; ++sub) {
                bf16x8 kf0 = __builtin_bit_cast(bf16x8, *(u16x8*)&Klds[(sub * 16 + li) * PAD + g * 8]);
                bf16x8 kf1 = __builtin_bit_cast(bf16x8, *(u16x8*)&Klds[(sub * 16 + li) * PAD + 32 + g * 8]);
                f32x4 c = f32x4{0.f, 0.f, 0.f, 0.f};
                c = __builtin_amdgcn_mfma_f32_16x16x32_bf16(qfrag[fi][0], kf0, c, 0, 0, 0);
                c = __builtin_amdgcn_mfma_f32_16x16x32_bf16(qfrag[fi][1], kf1, c, 0, 0, 0);
                sacc[sub] = c;
            }

            // ---- causal mask ----
            if (s0 + KBLK - 1 > qf) {
                #pragma unroll
                for (int sub = 0; sub < 4; ++sub)
                    #pragma unroll
                    for (int r = 0; r < 4; ++r) {
                        const int s = s0 + sub * 16 + li;
                        const int q = qf + g * 4 + r;
                        if (s > q) sacc[sub][r] = -1e30f;
                    }
            }

            // ---- online softmax ----
            float tmaxv[4];
            #pragma unroll
            for (int r = 0; r < 4; ++r)
                tmaxv[r] = fmaxf(fmaxf(sacc[0][r], sacc[1][r]), fmaxf(sacc[2][r], sacc[3][r]));
            #pragma unroll
            for (int r = 0; r < 4; ++r)
                #pragma unroll
                for (int msk = 1; msk < 16; msk <<= 1)
                    tmaxv[r] = fmaxf(tmaxv[r], __shfl_xor(tmaxv[r], msk));
            float alpha[4], rsum[4];
            unsigned short pb[4][4];
            #pragma unroll
            for (int r = 0; r < 4; ++r) {
                const float mnew = fmaxf(m_run[fi][r], tmaxv[r]);
                alpha[r] = __expf(m_run[fi][r] - mnew);
                m_run[fi][r] = mnew;
                rsum[r] = 0.f;
            }
            #pragma unroll
            for (int sub = 0; sub < 4; ++sub)
                #pragma unroll
                for (int r = 0; r < 4; ++r) {
                    const float pv = __expf(sacc[sub][r] - m_run[fi][r]);
                    rsum[r] += pv;
                    pb[sub][r] = f2bf(pv);
                }
            #pragma unroll
            for (int r = 0; r < 4; ++r) {
                #pragma unroll
                for (int msk = 1; msk < 16; msk <<= 1)
                    rsum[r] += __shfl_xor(rsum[r], msk);
                l_run[fi][r] = l_run[fi][r] * alpha[r] + rsum[r];
            }
            #pragma unroll
            for (int d = 0; d < 4; ++d)
                #pragma unroll
                for (int r = 0; r < 4; ++r) oacc[fi][d][r] *= alpha[r];

            // ---- P -> wave-private LDS ----
            unsigned short* pw = &Plds[(w * 32 + fi * 16) * PAD];
            #pragma unroll
            for (int sub = 0; sub < 4; ++sub)
                #pragma unroll
                for (int r = 0; r < 4; ++r)
                    pw[(g * 4 + r) * PAD + sub * 16 + li] = pb[sub][r];
        }

        // ---- PV (V-tile LDS reads shared between both frags) ----
        bf16x8 pf[2][2];
        #pragma unroll 2
        for (int fi = 0; fi < 2; ++fi) {
            if (fi == 0 && !act0) continue;
            pf[fi][0] = __builtin_bit_cast(bf16x8, *(u16x8*)&Plds[(w * 32 + fi * 16 + li) * PAD + g * 8]);
            pf[fi][1] = __builtin_bit_cast(bf16x8, *(u16x8*)&Plds[(w * 32 + fi * 16 + li) * PAD + 32 + g * 8]);
        }
        #pragma unroll
        for (int d = 0; d < 4; ++d) {
            bf16x8 vf0 = __builtin_bit_cast(bf16x8, *(u16x8*)&Vlds[(d * 16 + li) * PAD + g * 8]);
            bf16x8 vf1 = __builtin_bit_cast(bf16x8, *(u16x8*)&Vlds[(d * 16 + li) * PAD + 32 + g * 8]);
            #pragma unroll 2
            for (int fi = 0; fi < 2; ++fi) {
                if (fi == 0 && !act0) continue;
                oacc[fi][d] = __builtin_amdgcn_mfma_f32_16x16x32_bf16(pf[fi][0], vf0, oacc[fi][d], 0, 0, 0);
                oacc[fi][d] = __builtin_amdgcn_mfma_f32_16x16x32_bf16(pf[fi][1], vf1, oacc[fi][d], 0, 0, 0);
            }
        }
    }

    // ---- epilogue ----
    #pragma unroll 2
    for (int fi = 0; fi < 2; ++fi) {
        const int qf = (fi == 0) ? qrow0 : qrow1;
        #pragma unroll
        for (int r = 0; r < 4; ++r) {
            const int q = qf + g * 4 + r;
            const float inv = 1.0f / l_run[fi][r];
            float* op = Og + ((size_t)(b * SL + q) * NH + h) * HD + li;
            #pragma unroll
            for (int d = 0; d < 4; ++d)
                op[d * 16] = oacc[fi][d][r] * inv;
        }
    }
}

extern "C" void kernel_launch(void* const* d_in, const int* in_sizes, int n_in,
                              void* d_out, int out_size, void* d_ws, size_t ws_size,
                              hipStream_t stream) {
    const float* Qg = (const float*)d_in[0];
    const float* Kg = (const float*)d_in[1];
    const float* Vg = (const float*)d_in[2];
    float* Og = (float*)d_out;

    const size_t elems = (size_t)NB * NH * SL * HD;
    if (ws_size < 2 * elems * sizeof(unsigned short)) return;
    unsigned short* Kb  = (unsigned short*)d_ws;
    unsigned short* Vtb = Kb + elems;

    hipLaunchKernelGGL(conv_k, dim3(elems / 4 / 256), dim3(256), 0, stream, Kg, Kb);
    hipLaunchKernelGGL(conv_v, dim3(NB * NH * (SL / 64)), dim3(256), 0, stream, Vg, Vtb);
    hipLaunchKernelGGL(fattn_kernel, dim3((NT / 2) * 64), dim3(512), 0, stream,
                       Qg, Kb, Vtb, Og);
}

// Round 5
// 113.753 us; speedup vs baseline: 2.6515x; 1.4668x over previous
//
#include <hip/hip_runtime.h>
#include <hip/hip_bf16.h>

typedef float f32x4 __attribute__((ext_vector_type(4)));
typedef __bf16 bf16x8 __attribute__((ext_vector_type(8)));
typedef unsigned short u16x8 __attribute__((ext_vector_type(8)));
typedef unsigned short u16x4 __attribute__((ext_vector_type(4)));

#define NB 4
#define SL 2048
#define NH 16
#define HD 64
#define QBLK 128
#define KBLK 64
#define PAD 72
#define PSTRIDE 68
#define NT (SL / QBLK)

static __device__ __forceinline__ unsigned short f2bf(float f) {
    unsigned u = __builtin_bit_cast(unsigned, f);
    u += 0x7fffu + ((u >> 16) & 1u);
    return (unsigned short)(u >> 16);
}

// ---- prologue 1: K fp32 [b][s][h][e] -> bf16 [b][h][s][e] ----
__global__ void conv_k(const float* __restrict__ Kg, unsigned short* __restrict__ Kb) {
    const int idx = (blockIdx.x * 256 + threadIdx.x) * 4;
    const int e    = idx & 63;
    const int rest = idx >> 6;
    const int h    = rest & 15;
    const int bs   = rest >> 4;
    const int b    = bs >> 11;
    const int s    = bs & (SL - 1);
    f32x4 v = *(const f32x4*)(Kg + idx);
    u16x4 o;
    #pragma unroll
    for (int j = 0; j < 4; ++j) o[j] = f2bf(v[j]);
    *(u16x4*)(Kb + (((size_t)(b * NH + h) * SL + s) * HD + e)) = o;
}

// ---- prologue 2: V fp32 [b][s][h][d] -> bf16 transposed [b][h][d][s] ----
__global__ void conv_v(const float* __restrict__ Vg, unsigned short* __restrict__ Vtb) {
    __shared__ unsigned short T[64 * PAD];
    const int tid = threadIdx.x;
    const int id  = blockIdx.x;
    const int st  = id & 31;
    const int bh  = id >> 5;
    const int s0  = st * 64;
    {
        const int sl = tid >> 2, c = (tid & 3) * 16;
        const float* src = Vg + ((size_t)((bh >> 4) * SL + s0 + sl) * NH + (bh & 15)) * HD + c;
        u16x8 a, b2;
        #pragma unroll
        for (int j = 0; j < 8; ++j) { a[j] = f2bf(src[j]); b2[j] = f2bf(src[8 + j]); }
        *(u16x8*)&T[sl * PAD + c]     = a;
        *(u16x8*)&T[sl * PAD + c + 8] = b2;
    }
    __syncthreads();
    {
        const int d = tid >> 2, sc = (tid & 3) * 16;
        u16x8 o0, o1;
        #pragma unroll
        for (int j = 0; j < 8; ++j) { o0[j] = T[(sc + j) * PAD + d]; o1[j] = T[(sc + 8 + j) * PAD + d]; }
        unsigned short* dst = Vtb + ((size_t)bh * HD + d) * SL + s0 + sc;
        *(u16x8*)dst       = o0;
        *(u16x8*)(dst + 8) = o1;
    }
}

// ---- main: paired causal q-tiles, swapped-QK^T in-register softmax (bisect build) ----
__global__ __launch_bounds__(512, 4)
void fattn_kernel(const float* __restrict__ Qg, const unsigned short* __restrict__ Kb,
                  const unsigned short* __restrict__ Vtb, float* __restrict__ Og)
{
    __shared__ unsigned short Klds[KBLK * PAD];
    __shared__ unsigned short Vlds[HD * PAD];
    __shared__ __align__(16) float Plds[8 * 16 * PSTRIDE];

    const int tid  = threadIdx.x;
    const int w    = tid >> 6;
    const int lane = tid & 63;
    const int g    = lane >> 4;
    const int li   = lane & 15;

    const int bh   = blockIdx.x & 63;
    const int rawp = blockIdx.x >> 6;
    const int p    = (rawp < 4) ? rawp : 11 - rawp;
    const int b    = bh >> 4;
    const int h    = bh & 15;

    const int qrow0 = p * QBLK + w * 16;
    const int qrow1 = (NT - 1 - p) * QBLK + w * 16;
    const int tmax  = 2 * (NT - 1 - p) + 1;

    const float QSCALE = 0.125f * 1.44269504088896f;  // (1/sqrt64)*log2(e)
    bf16x8 qfrag[2][2];
    #pragma unroll
    for (int fi = 0; fi < 2; ++fi) {
        const int q = (fi == 0 ? qrow0 : qrow1) + li;
        const float* qp = Qg + ((size_t)(b * SL + q) * NH + h) * HD + g * 8;
        #pragma unroll
        for (int c = 0; c < 2; ++c) {
            f32x4 a = *(const f32x4*)(qp + c * 32);
            f32x4 b2 = *(const f32x4*)(qp + c * 32 + 4);
            u16x8 t;
            #pragma unroll
            for (int j = 0; j < 4; ++j) { t[j] = f2bf(a[j] * QSCALE); t[4 + j] = f2bf(b2[j] * QSCALE); }
            qfrag[fi][c] = __builtin_bit_cast(bf16x8, t);
        }
    }

    float m_run[2] = {-1e30f, -1e30f};
    float l_run[2] = {0.f, 0.f};
    f32x4 oacc[2][4];
    #pragma unroll
    for (int fi = 0; fi < 2; ++fi)
        #pragma unroll
        for (int d = 0; d < 4; ++d) oacc[fi][d] = f32x4{0.f, 0.f, 0.f, 0.f};

    const int srow = tid >> 3;
    const int scol = (tid & 7) * 8;
    const unsigned short* kbase = Kb  + (size_t)bh * SL * HD;
    const unsigned short* vbase = Vtb + (size_t)bh * HD * SL;
    float* const pw = &Plds[w * 16 * PSTRIDE];

    u16x8 kreg = *(const u16x8*)(kbase + (size_t)srow * HD + scol);
    u16x8 vreg = *(const u16x8*)(vbase + (size_t)srow * SL + scol);

    for (int t = 0; t <= tmax; ++t) {
        const int s0 = t * KBLK;
        __syncthreads();
        *(u16x8*)&Klds[srow * PAD + scol] = kreg;
        *(u16x8*)&Vlds[srow * PAD + scol] = vreg;
        if (t < tmax) {
            const int s1 = s0 + KBLK;
            kreg = *(const u16x8*)(kbase + ((size_t)(s1 + srow)) * HD + scol);
            vreg = *(const u16x8*)(vbase + (size_t)srow * SL + s1 + scol);
        }
        __syncthreads();

        const bool act0 = (s0 <= qrow0 + 15);
        bf16x8 pfr[2][2];

        #pragma unroll
        for (int fi = 0; fi < 2; ++fi) {
            if (fi == 0 && !act0) continue;
            const int qf = (fi == 0) ? qrow0 : qrow1;

            // S^T = K Q^T : lane holds col q=qf+li, rows s = s0+sub*16+g*4+r
            f32x4 sacc[4];
            #pragma unroll
            for (int sub = 0; sub < 4; ++sub) {
                bf16x8 kf0 = __builtin_bit_cast(bf16x8, *(u16x8*)&Klds[(sub * 16 + li) * PAD + g * 8]);
                bf16x8 kf1 = __builtin_bit_cast(bf16x8, *(u16x8*)&Klds[(sub * 16 + li) * PAD + 32 + g * 8]);
                f32x4 c = f32x4{0.f, 0.f, 0.f, 0.f};
                c = __builtin_amdgcn_mfma_f32_16x16x32_bf16(kf0, qfrag[fi][0], c, 0, 0, 0);
                c = __builtin_amdgcn_mfma_f32_16x16x32_bf16(kf1, qfrag[fi][1], c, 0, 0, 0);
                sacc[sub] = c;
            }

            // causal mask: s > q
            if (s0 + KBLK - 1 > qf) {
                const int q = qf + li;
                #pragma unroll
                for (int sub = 0; sub < 4; ++sub)
                    #pragma unroll
                    for (int r = 0; r < 4; ++r)
                        if (s0 + sub * 16 + g * 4 + r > q) sacc[sub][r] = -1e30f;
            }

            // row max: 15 in-reg + 2 cross-lane (explicit width 64)
            float pmax = sacc[0][0];
            #pragma unroll
            for (int sub = 0; sub < 4; ++sub)
                #pragma unroll
                for (int r = 0; r < 4; ++r) pmax = fmaxf(pmax, sacc[sub][r]);
            pmax = fmaxf(pmax, __shfl_xor(pmax, 16, 64));
            pmax = fmaxf(pmax, __shfl_xor(pmax, 32, 64));

            // plain online-softmax rescale (no defer-max in this bisect build)
            const float mnew = fmaxf(m_run[fi], pmax);
            const float alpha = exp2f(m_run[fi] - mnew);
            m_run[fi] = mnew;
            l_run[fi] *= alpha;
            #pragma unroll
            for (int d = 0; d < 4; ++d)
                #pragma unroll
                for (int r = 0; r < 4; ++r) oacc[fi][d][r] *= alpha;

            // P = 2^(S-m), row sum
            float rsum = 0.f;
            #pragma unroll
            for (int sub = 0; sub < 4; ++sub)
                #pragma unroll
                for (int r = 0; r < 4; ++r) {
                    const float pv = exp2f(sacc[sub][r] - m_run[fi]);
                    sacc[sub][r] = pv;
                    rsum += pv;
                }
            rsum += __shfl_xor(rsum, 16, 64);
            rsum += __shfl_xor(rsum, 32, 64);
            l_run[fi] += rsum;

            // P (f32) -> LDS [q=li][s], then refragment (f2bf pack, known-good)
            #pragma unroll
            for (int sub = 0; sub < 4; ++sub)
                *(f32x4*)&pw[li * PSTRIDE + sub * 16 + g * 4] = sacc[sub];
            asm volatile("s_waitcnt lgkmcnt(0)" ::: "memory");
            #pragma unroll
            for (int c = 0; c < 2; ++c) {
                f32x4 a = *(const f32x4*)&pw[li * PSTRIDE + c * 32 + g * 8];
                f32x4 b2 = *(const f32x4*)&pw[li * PSTRIDE + c * 32 + g * 8 + 4];
                u16x8 tt;
                #pragma unroll
                for (int j = 0; j < 4; ++j) { tt[j] = f2bf(a[j]); tt[4 + j] = f2bf(b2[j]); }
                pfr[fi][c] = __builtin_bit_cast(bf16x8, tt);
            }
            asm volatile("s_waitcnt lgkmcnt(0)" ::: "memory");
        }

        // PV: oacc += V^T x P  (V-frags shared across both fi)
        #pragma unroll
        for (int d = 0; d < 4; ++d) {
            bf16x8 vf0 = __builtin_bit_cast(bf16x8, *(u16x8*)&Vlds[(d * 16 + li) * PAD + g * 8]);
            bf16x8 vf1 = __builtin_bit_cast(bf16x8, *(u16x8*)&Vlds[(d * 16 + li) * PAD + 32 + g * 8]);
            #pragma unroll
            for (int fi = 0; fi < 2; ++fi) {
                if (fi == 0 && !act0) continue;
                oacc[fi][d] = __builtin_amdgcn_mfma_f32_16x16x32_bf16(vf0, pfr[fi][0], oacc[fi][d], 0, 0, 0);
                oacc[fi][d] = __builtin_amdgcn_mfma_f32_16x16x32_bf16(vf1, pfr[fi][1], oacc[fi][d], 0, 0, 0);
            }
        }
    }

    // epilogue: lane owns q-row qf+li, cols dd = d*16 + g*4 + r
    #pragma unroll
    for (int fi = 0; fi < 2; ++fi) {
        const int qf = (fi == 0) ? qrow0 : qrow1;
        const float inv = 1.0f / l_run[fi];
        float* op = Og + ((size_t)(b * SL + qf + li) * NH + h) * HD + g * 4;
        #pragma unroll
        for (int d = 0; d < 4; ++d) {
            f32x4 o = oacc[fi][d];
            #pragma unroll
            for (int r = 0; r < 4; ++r) o[r] *= inv;
            *(f32x4*)(op + d * 16) = o;
        }
    }
}

extern "C" void kernel_launch(void* const* d_in, const int* in_sizes, int n_in,
                              void* d_out, int out_size, void* d_ws, size_t ws_size,
                              hipStream_t stream) {
    const float* Qg = (const float*)d_in[0];
    const float* Kg = (const float*)d_in[1];
    const float* Vg = (const float*)d_in[2];
    float* Og = (float*)d_out;

    const size_t elems = (size_t)NB * NH * SL * HD;
    if (ws_size < 2 * elems * sizeof(unsigned short)) return;
    unsigned short* Kb  = (unsigned short*)d_ws;
    unsigned short* Vtb = Kb + elems;

    hipLaunchKernelGGL(conv_k, dim3(elems / 4 / 256), dim3(256), 0, stream, Kg, Kb);
    hipLaunchKernelGGL(conv_v, dim3(NB * NH * (SL / 64)), dim3(256), 0, stream, Vg, Vtb);
    hipLaunchKernelGGL(fattn_kernel, dim3((NT / 2) * 64), dim3(512), 0, stream,
                       Qg, Kb, Vtb, Og);
}

// Round 6
// 98.327 us; speedup vs baseline: 3.0675x; 1.1569x over previous
//
#include <hip/hip_runtime.h>
#include <hip/hip_bf16.h>

typedef float f32x4 __attribute__((ext_vector_type(4)));
typedef __bf16 bf16x8 __attribute__((ext_vector_type(8)));
typedef unsigned short u16x8 __attribute__((ext_vector_type(8)));
typedef unsigned short u16x4 __attribute__((ext_vector_type(4)));
typedef unsigned u32x2 __attribute__((ext_vector_type(2)));
typedef unsigned u32x4 __attribute__((ext_vector_type(4)));

#define NB 4
#define SL 2048
#define NH 16
#define HD 64
#define QBLK 128
#define KBLK 64
#define PAD 72
#define PSW 36              // u32 words per P row (16B-aligned rows: 144B = 16*9)
#define NT (SL / QBLK)

static __device__ __forceinline__ unsigned short f2bf(float f) {
    unsigned u = __builtin_bit_cast(unsigned, f);
    u += 0x7fffu + ((u >> 16) & 1u);
    return (unsigned short)(u >> 16);
}

static __device__ __forceinline__ unsigned pk2(float lo, float hi) {
    unsigned r;
    asm("v_cvt_pk_bf16_f32 %0, %1, %2" : "=v"(r) : "v"(lo), "v"(hi));
    return r;
}

// ---- prologue 1: K fp32 [b][s][h][e] -> bf16 [b][h][s][e] ----
__global__ void conv_k(const float* __restrict__ Kg, unsigned short* __restrict__ Kb) {
    const int idx = (blockIdx.x * 256 + threadIdx.x) * 4;
    const int e    = idx & 63;
    const int rest = idx >> 6;
    const int h    = rest & 15;
    const int bs   = rest >> 4;
    const int b    = bs >> 11;
    const int s    = bs & (SL - 1);
    f32x4 v = *(const f32x4*)(Kg + idx);
    u16x4 o;
    #pragma unroll
    for (int j = 0; j < 4; ++j) o[j] = f2bf(v[j]);
    *(u16x4*)(Kb + (((size_t)(b * NH + h) * SL + s) * HD + e)) = o;
}

// ---- prologue 2: V fp32 [b][s][h][d] -> bf16 transposed [b][h][d][s] ----
__global__ void conv_v(const float* __restrict__ Vg, unsigned short* __restrict__ Vtb) {
    __shared__ unsigned short T[64 * PAD];
    const int tid = threadIdx.x;
    const int id  = blockIdx.x;
    const int st  = id & 31;
    const int bh  = id >> 5;
    const int s0  = st * 64;
    {
        const int sl = tid >> 2, c = (tid & 3) * 16;
        const float* src = Vg + ((size_t)((bh >> 4) * SL + s0 + sl) * NH + (bh & 15)) * HD + c;
        u16x8 a, b2;
        #pragma unroll
        for (int j = 0; j < 8; ++j) { a[j] = f2bf(src[j]); b2[j] = f2bf(src[8 + j]); }
        *(u16x8*)&T[sl * PAD + c]     = a;
        *(u16x8*)&T[sl * PAD + c + 8] = b2;
    }
    __syncthreads();
    {
        const int d = tid >> 2, sc = (tid & 3) * 16;
        u16x8 o0, o1;
        #pragma unroll
        for (int j = 0; j < 8; ++j) { o0[j] = T[(sc + j) * PAD + d]; o1[j] = T[(sc + 8 + j) * PAD + d]; }
        unsigned short* dst = Vtb + ((size_t)bh * HD + d) * SL + s0 + sc;
        *(u16x8*)dst       = o0;
        *(u16x8*)(dst + 8) = o1;
    }
}

// ---- main: paired causal q-tiles, swapped-QK^T, packed-P roundtrip ----
__global__ __launch_bounds__(512, 4)
void fattn_kernel(const float* __restrict__ Qg, const unsigned short* __restrict__ Kb,
                  const unsigned short* __restrict__ Vtb, float* __restrict__ Og)
{
    __shared__ unsigned short Klds[KBLK * PAD];
    __shared__ unsigned short Vlds[HD * PAD];
    __shared__ __align__(16) unsigned Plds[8 * 16 * PSW];   // packed bf16x2 P per wave

    const int tid  = threadIdx.x;
    const int w    = tid >> 6;
    const int lane = tid & 63;
    const int g    = lane >> 4;
    const int li   = lane & 15;

    const int bh   = blockIdx.x & 63;
    const int rawp = blockIdx.x >> 6;
    const int p    = (rawp < 4) ? rawp : 11 - rawp;
    const int b    = bh >> 4;
    const int h    = bh & 15;

    const int qrow0 = p * QBLK + w * 16;
    const int qrow1 = (NT - 1 - p) * QBLK + w * 16;
    const int tmax  = 2 * (NT - 1 - p) + 1;

    const float QSCALE = 0.125f * 1.44269504088896f;  // (1/sqrt64)*log2(e)
    bf16x8 qfrag[2][2];
    #pragma unroll
    for (int fi = 0; fi < 2; ++fi) {
        const int q = (fi == 0 ? qrow0 : qrow1) + li;
        const float* qp = Qg + ((size_t)(b * SL + q) * NH + h) * HD + g * 8;
        #pragma unroll
        for (int c = 0; c < 2; ++c) {
            f32x4 a = *(const f32x4*)(qp + c * 32);
            f32x4 b2 = *(const f32x4*)(qp + c * 32 + 4);
            u16x8 t;
            #pragma unroll
            for (int j = 0; j < 4; ++j) { t[j] = f2bf(a[j] * QSCALE); t[4 + j] = f2bf(b2[j] * QSCALE); }
            qfrag[fi][c] = __builtin_bit_cast(bf16x8, t);
        }
    }

    float m_run[2] = {-1e30f, -1e30f};
    float l_run[2] = {0.f, 0.f};
    f32x4 oacc[2][4];
    #pragma unroll
    for (int fi = 0; fi < 2; ++fi)
        #pragma unroll
        for (int d = 0; d < 4; ++d) oacc[fi][d] = f32x4{0.f, 0.f, 0.f, 0.f};

    const int srow = tid >> 3;
    const int scol = (tid & 7) * 8;
    const unsigned short* kbase = Kb  + (size_t)bh * SL * HD;
    const unsigned short* vbase = Vtb + (size_t)bh * HD * SL;
    unsigned* const pw = &Plds[w * 16 * PSW];

    u16x8 kreg = *(const u16x8*)(kbase + (size_t)srow * HD + scol);
    u16x8 vreg = *(const u16x8*)(vbase + (size_t)srow * SL + scol);

    for (int t = 0; t <= tmax; ++t) {
        const int s0 = t * KBLK;
        __syncthreads();
        *(u16x8*)&Klds[srow * PAD + scol] = kreg;
        *(u16x8*)&Vlds[srow * PAD + scol] = vreg;
        if (t < tmax) {
            const int s1 = s0 + KBLK;
            kreg = *(const u16x8*)(kbase + ((size_t)(s1 + srow)) * HD + scol);
            vreg = *(const u16x8*)(vbase + (size_t)srow * SL + s1 + scol);
        }
        __syncthreads();

        const bool act0 = (s0 <= qrow0 + 15);
        bf16x8 pfr[2][2];

        #pragma unroll
        for (int fi = 0; fi < 2; ++fi) {
            if (fi == 0 && !act0) continue;
            const int qf = (fi == 0) ? qrow0 : qrow1;

            // S^T = K Q^T : lane holds col q=qf+li, rows s = s0+sub*16+g*4+r
            f32x4 sacc[4];
            #pragma unroll
            for (int sub = 0; sub < 4; ++sub) {
                bf16x8 kf0 = __builtin_bit_cast(bf16x8, *(u16x8*)&Klds[(sub * 16 + li) * PAD + g * 8]);
                bf16x8 kf1 = __builtin_bit_cast(bf16x8, *(u16x8*)&Klds[(sub * 16 + li) * PAD + 32 + g * 8]);
                f32x4 c = f32x4{0.f, 0.f, 0.f, 0.f};
                c = __builtin_amdgcn_mfma_f32_16x16x32_bf16(kf0, qfrag[fi][0], c, 0, 0, 0);
                c = __builtin_amdgcn_mfma_f32_16x16x32_bf16(kf1, qfrag[fi][1], c, 0, 0, 0);
                sacc[sub] = c;
            }

            // causal mask: s > q
            if (s0 + KBLK - 1 > qf) {
                const int q = qf + li;
                #pragma unroll
                for (int sub = 0; sub < 4; ++sub)
                    #pragma unroll
                    for (int r = 0; r < 4; ++r)
                        if (s0 + sub * 16 + g * 4 + r > q) sacc[sub][r] = -1e30f;
            }

            // row max: 15 in-reg + 2 cross-lane
            float pmax = sacc[0][0];
            #pragma unroll
            for (int sub = 0; sub < 4; ++sub)
                #pragma unroll
                for (int r = 0; r < 4; ++r) pmax = fmaxf(pmax, sacc[sub][r]);
            pmax = fmaxf(pmax, __shfl_xor(pmax, 16, 64));
            pmax = fmaxf(pmax, __shfl_xor(pmax, 32, 64));

            // defer-max (T13): rescale only when max grew past THR=8
            if (!__all(pmax - m_run[fi] <= 8.0f)) {
                const float mnew = fmaxf(m_run[fi], pmax);
                const float alpha = exp2f(m_run[fi] - mnew);
                m_run[fi] = mnew;
                l_run[fi] *= alpha;
                #pragma unroll
                for (int d = 0; d < 4; ++d)
                    #pragma unroll
                    for (int r = 0; r < 4; ++r) oacc[fi][d][r] *= alpha;
            }

            // P = 2^(S-m), row sum, pack to bf16 pairs in-register
            float rsum = 0.f;
            #pragma unroll
            for (int sub = 0; sub < 4; ++sub)
                #pragma unroll
                for (int r = 0; r < 4; ++r) {
                    const float pv = exp2f(sacc[sub][r] - m_run[fi]);
                    sacc[sub][r] = pv;
                    rsum += pv;
                }
            rsum += __shfl_xor(rsum, 16, 64);
            rsum += __shfl_xor(rsum, 32, 64);
            l_run[fi] += rsum;

            // packed P -> LDS: word ws=s/2 at row li; write pairs (even->lo)
            #pragma unroll
            for (int sub = 0; sub < 4; ++sub) {
                u32x2 wv;
                wv[0] = pk2(sacc[sub][0], sacc[sub][1]);
                wv[1] = pk2(sacc[sub][2], sacc[sub][3]);
                *(u32x2*)&pw[li * PSW + sub * 8 + g * 2] = wv;
            }
            asm volatile("s_waitcnt lgkmcnt(0)" ::: "memory");
            #pragma unroll
            for (int c = 0; c < 2; ++c) {
                u32x4 tt = *(const u32x4*)&pw[li * PSW + c * 16 + g * 4];
                pfr[fi][c] = __builtin_bit_cast(bf16x8, tt);
            }
            asm volatile("s_waitcnt lgkmcnt(0)" ::: "memory");
        }

        // PV: oacc += V^T x P  (V-frags shared across both fi)
        #pragma unroll
        for (int d = 0; d < 4; ++d) {
            bf16x8 vf0 = __builtin_bit_cast(bf16x8, *(u16x8*)&Vlds[(d * 16 + li) * PAD + g * 8]);
            bf16x8 vf1 = __builtin_bit_cast(bf16x8, *(u16x8*)&Vlds[(d * 16 + li) * PAD + 32 + g * 8]);
            #pragma unroll
            for (int fi = 0; fi < 2; ++fi) {
                if (fi == 0 && !act0) continue;
                oacc[fi][d] = __builtin_amdgcn_mfma_f32_16x16x32_bf16(vf0, pfr[fi][0], oacc[fi][d], 0, 0, 0);
                oacc[fi][d] = __builtin_amdgcn_mfma_f32_16x16x32_bf16(vf1, pfr[fi][1], oacc[fi][d], 0, 0, 0);
            }
        }
    }

    // epilogue: lane owns q-row qf+li, cols dd = d*16 + g*4 + r
    #pragma unroll
    for (int fi = 0; fi < 2; ++fi) {
        const int qf = (fi == 0) ? qrow0 : qrow1;
        const float inv = 1.0f / l_run[fi];
        float* op = Og + ((size_t)(b * SL + qf + li) * NH + h) * HD + g * 4;
        #pragma unroll
        for (int d = 0; d < 4; ++d) {
            f32x4 o = oacc[fi][d];
            #pragma unroll
            for (int r = 0; r < 4; ++r) o[r] *= inv;
            *(f32x4*)(op + d * 16) = o;
        }
    }
}

extern "C" void kernel_launch(void* const* d_in, const int* in_sizes, int n_in,
                              void* d_out, int out_size, void* d_ws, size_t ws_size,
                              hipStream_t stream) {
    const float* Qg = (const float*)d_in[0];
    const float* Kg = (const float*)d_in[1];
    const float* Vg = (const float*)d_in[2];
    float* Og = (float*)d_out;

    const size_t elems = (size_t)NB * NH * SL * HD;
    if (ws_size < 2 * elems * sizeof(unsigned short)) return;
    unsigned short* Kb  = (unsigned short*)d_ws;
    unsigned short* Vtb = Kb + elems;

    hipLaunchKernelGGL(conv_k, dim3(elems / 4 / 256), dim3(256), 0, stream, Kg, Kb);
    hipLaunchKernelGGL(conv_v, dim3(NB * NH * (SL / 64)), dim3(256), 0, stream, Vg, Vtb);
    hipLaunchKernelGGL(fattn_kernel, dim3((NT / 2) * 64), dim3(512), 0, stream,
                       Qg, Kb, Vtb, Og);
}

// Round 7
// 97.607 us; speedup vs baseline: 3.0901x; 1.0074x over previous
//
#include <hip/hip_runtime.h>
#include <hip/hip_bf16.h>

typedef float f32x4 __attribute__((ext_vector_type(4)));
typedef __bf16 bf16x8 __attribute__((ext_vector_type(8)));
typedef unsigned short u16x8 __attribute__((ext_vector_type(8)));
typedef unsigned short u16x4 __attribute__((ext_vector_type(4)));
typedef unsigned u32x4 __attribute__((ext_vector_type(4)));

#define NB 4
#define SL 2048
#define NH 16
#define HD 64
#define QBLK 128
#define KBLK 64
#define PAD 72
#define NT (SL / QBLK)

static __device__ __forceinline__ unsigned short f2bf(float f) {
    unsigned u = __builtin_bit_cast(unsigned, f);
    u += 0x7fffu + ((u >> 16) & 1u);
    return (unsigned short)(u >> 16);
}

static __device__ __forceinline__ unsigned pk2(float lo, float hi) {
    unsigned r;
    asm("v_cvt_pk_bf16_f32 %0, %1, %2" : "=v"(r) : "v"(lo), "v"(hi));
    return r;
}

// v_permlane32_swap_b32: new_a = [a.lo32 | b.lo32], new_b = [a.hi32 | b.hi32]
static __device__ __forceinline__ void pl32swap(unsigned& a, unsigned& b) {
    asm("v_permlane32_swap_b32 %0, %1" : "+v"(a), "+v"(b));
}
// v_permlane16_swap_b32: swaps a's odd 16-lane rows with b's even rows:
// new_a = [a.r0, b.r0... actually a.r0, b_even->..]: net [a.r0, b.r0_src...]
// semantics used: new_a = [a.r0, a_prev_b.r0? ] -> derived mapping:
// new_a = [a.r0, b.r0, a.r2, b.r2], new_b = [a.r1, b.r1, a.r3, b.r3]
static __device__ __forceinline__ void pl16swap(unsigned& a, unsigned& b) {
    asm("v_permlane16_swap_b32 %0, %1" : "+v"(a), "+v"(b));
}

// ---- prologue 1: K fp32 [b][s][h][e] -> bf16 [b][h][s][e] ----
__global__ void conv_k(const float* __restrict__ Kg, unsigned short* __restrict__ Kb) {
    const int idx = (blockIdx.x * 256 + threadIdx.x) * 4;
    const int e    = idx & 63;
    const int rest = idx >> 6;
    const int h    = rest & 15;
    const int bs   = rest >> 4;
    const int b    = bs >> 11;
    const int s    = bs & (SL - 1);
    f32x4 v = *(const f32x4*)(Kg + idx);
    u16x4 o;
    #pragma unroll
    for (int j = 0; j < 4; ++j) o[j] = f2bf(v[j]);
    *(u16x4*)(Kb + (((size_t)(b * NH + h) * SL + s) * HD + e)) = o;
}

// ---- prologue 2: V fp32 [b][s][h][d] -> bf16 transposed [b][h][d][s] ----
__global__ void conv_v(const float* __restrict__ Vg, unsigned short* __restrict__ Vtb) {
    __shared__ unsigned short T[64 * PAD];
    const int tid = threadIdx.x;
    const int id  = blockIdx.x;
    const int st  = id & 31;
    const int bh  = id >> 5;
    const int s0  = st * 64;
    {
        const int sl = tid >> 2, c = (tid & 3) * 16;
        const float* src = Vg + ((size_t)((bh >> 4) * SL + s0 + sl) * NH + (bh & 15)) * HD + c;
        u16x8 a, b2;
        #pragma unroll
        for (int j = 0; j < 8; ++j) { a[j] = f2bf(src[j]); b2[j] = f2bf(src[8 + j]); }
        *(u16x8*)&T[sl * PAD + c]     = a;
        *(u16x8*)&T[sl * PAD + c + 8] = b2;
    }
    __syncthreads();
    {
        const int d = tid >> 2, sc = (tid & 3) * 16;
        u16x8 o0, o1;
        #pragma unroll
        for (int j = 0; j < 8; ++j) { o0[j] = T[(sc + j) * PAD + d]; o1[j] = T[(sc + 8 + j) * PAD + d]; }
        unsigned short* dst = Vtb + ((size_t)bh * HD + d) * SL + s0 + sc;
        *(u16x8*)dst       = o0;
        *(u16x8*)(dst + 8) = o1;
    }
}

// ---- main: paired causal q-tiles, swapped-QK^T, permlane P-exchange ----
__global__ __launch_bounds__(512, 4)
void fattn_kernel(const float* __restrict__ Qg, const unsigned short* __restrict__ Kb,
                  const unsigned short* __restrict__ Vtb, float* __restrict__ Og)
{
    __shared__ unsigned short Klds[KBLK * PAD];
    __shared__ unsigned short Vlds[HD * PAD];

    const int tid  = threadIdx.x;
    const int w    = tid >> 6;
    const int lane = tid & 63;
    const int g    = lane >> 4;
    const int li   = lane & 15;

    const int bh   = blockIdx.x & 63;
    const int rawp = blockIdx.x >> 6;
    const int p    = (rawp < 4) ? rawp : 11 - rawp;
    const int b    = bh >> 4;
    const int h    = bh & 15;

    const int qrow0 = p * QBLK + w * 16;
    const int qrow1 = (NT - 1 - p) * QBLK + w * 16;
    const int tmax  = 2 * (NT - 1 - p) + 1;

    const float QSCALE = 0.125f * 1.44269504088896f;  // (1/sqrt64)*log2(e)
    bf16x8 qfrag[2][2];
    #pragma unroll
    for (int fi = 0; fi < 2; ++fi) {
        const int q = (fi == 0 ? qrow0 : qrow1) + li;
        const float* qp = Qg + ((size_t)(b * SL + q) * NH + h) * HD + g * 8;
        #pragma unroll
        for (int c = 0; c < 2; ++c) {
            f32x4 a = *(const f32x4*)(qp + c * 32);
            f32x4 b2 = *(const f32x4*)(qp + c * 32 + 4);
            u16x8 t;
            #pragma unroll
            for (int j = 0; j < 4; ++j) { t[j] = f2bf(a[j] * QSCALE); t[4 + j] = f2bf(b2[j] * QSCALE); }
            qfrag[fi][c] = __builtin_bit_cast(bf16x8, t);
        }
    }

    float m_run[2] = {-1e30f, -1e30f};
    float l_run[2] = {0.f, 0.f};
    f32x4 oacc[2][4];
    #pragma unroll
    for (int fi = 0; fi < 2; ++fi)
        #pragma unroll
        for (int d = 0; d < 4; ++d) oacc[fi][d] = f32x4{0.f, 0.f, 0.f, 0.f};

    const int srow = tid >> 3;
    const int scol = (tid & 7) * 8;
    const unsigned short* kbase = Kb  + (size_t)bh * SL * HD;
    const unsigned short* vbase = Vtb + (size_t)bh * HD * SL;

    u16x8 kreg = *(const u16x8*)(kbase + (size_t)srow * HD + scol);
    u16x8 vreg = *(const u16x8*)(vbase + (size_t)srow * SL + scol);

    for (int t = 0; t <= tmax; ++t) {
        const int s0 = t * KBLK;
        __syncthreads();
        *(u16x8*)&Klds[srow * PAD + scol] = kreg;
        *(u16x8*)&Vlds[srow * PAD + scol] = vreg;
        if (t < tmax) {
            const int s1 = s0 + KBLK;
            kreg = *(const u16x8*)(kbase + ((size_t)(s1 + srow)) * HD + scol);
            vreg = *(const u16x8*)(vbase + (size_t)srow * SL + s1 + scol);
        }
        __syncthreads();

        const bool act0 = (s0 <= qrow0 + 15);
        bf16x8 pfr[2][2];

        #pragma unroll
        for (int fi = 0; fi < 2; ++fi) {
            if (fi == 0 && !act0) continue;
            const int qf = (fi == 0) ? qrow0 : qrow1;

            // S^T = K Q^T : lane holds col q=qf+li, rows s = s0+sub*16+g*4+r
            f32x4 sacc[4];
            #pragma unroll
            for (int sub = 0; sub < 4; ++sub) {
                bf16x8 kf0 = __builtin_bit_cast(bf16x8, *(u16x8*)&Klds[(sub * 16 + li) * PAD + g * 8]);
                bf16x8 kf1 = __builtin_bit_cast(bf16x8, *(u16x8*)&Klds[(sub * 16 + li) * PAD + 32 + g * 8]);
                f32x4 c = f32x4{0.f, 0.f, 0.f, 0.f};
                c = __builtin_amdgcn_mfma_f32_16x16x32_bf16(kf0, qfrag[fi][0], c, 0, 0, 0);
                c = __builtin_amdgcn_mfma_f32_16x16x32_bf16(kf1, qfrag[fi][1], c, 0, 0, 0);
                sacc[sub] = c;
            }

            // causal mask: s > q
            if (s0 + KBLK - 1 > qf) {
                const int q = qf + li;
                #pragma unroll
                for (int sub = 0; sub < 4; ++sub)
                    #pragma unroll
                    for (int r = 0; r < 4; ++r)
                        if (s0 + sub * 16 + g * 4 + r > q) sacc[sub][r] = -1e30f;
            }

            // row max: 15 in-reg + 2 cross-lane
            float pmax = sacc[0][0];
            #pragma unroll
            for (int sub = 0; sub < 4; ++sub)
                #pragma unroll
                for (int r = 0; r < 4; ++r) pmax = fmaxf(pmax, sacc[sub][r]);
            pmax = fmaxf(pmax, __shfl_xor(pmax, 16, 64));
            pmax = fmaxf(pmax, __shfl_xor(pmax, 32, 64));

            // defer-max (T13): rescale only when max grew past THR=8
            if (!__all(pmax - m_run[fi] <= 8.0f)) {
                const float mnew = fmaxf(m_run[fi], pmax);
                const float alpha = exp2f(m_run[fi] - mnew);
                m_run[fi] = mnew;
                l_run[fi] *= alpha;
                #pragma unroll
                for (int d = 0; d < 4; ++d)
                    #pragma unroll
                    for (int r = 0; r < 4; ++r) oacc[fi][d][r] *= alpha;
            }

            // P = 2^(S-m), row sum
            float rsum = 0.f;
            #pragma unroll
            for (int sub = 0; sub < 4; ++sub)
                #pragma unroll
                for (int r = 0; r < 4; ++r) {
                    const float pv = exp2f(sacc[sub][r] - m_run[fi]);
                    sacc[sub][r] = pv;
                    rsum += pv;
                }
            rsum += __shfl_xor(rsum, 16, 64);
            rsum += __shfl_xor(rsum, 32, 64);
            l_run[fi] += rsum;

            // ---- in-register P exchange: pack + permlane (no LDS) ----
            // X[sub][i] = bf16 pair of (sacc[sub][2i], sacc[sub][2i+1])
            unsigned X00 = pk2(sacc[0][0], sacc[0][1]);
            unsigned X01 = pk2(sacc[0][2], sacc[0][3]);
            unsigned X10 = pk2(sacc[1][0], sacc[1][1]);
            unsigned X11 = pk2(sacc[1][2], sacc[1][3]);
            unsigned X20 = pk2(sacc[2][0], sacc[2][1]);
            unsigned X21 = pk2(sacc[2][2], sacc[2][3]);
            unsigned X30 = pk2(sacc[3][0], sacc[3][1]);
            unsigned X31 = pk2(sacc[3][2], sacc[3][3]);
            // (Xa, Xb) -> permlane32_swap -> permlane16_swap yields
            // a' = rows [a.g0, a.g2, b.g0, b.g2]  (dest word pos)
            // b' = rows [a.g1, a.g3, b.g1, b.g3]  (dest word pos+2)
            pl32swap(X00, X10); pl16swap(X00, X10);   // -> kf0 w0, w2
            pl32swap(X01, X11); pl16swap(X01, X11);   // -> kf0 w1, w3
            pl32swap(X20, X30); pl16swap(X20, X30);   // -> kf1 w0, w2
            pl32swap(X21, X31); pl16swap(X21, X31);   // -> kf1 w1, w3
            u32x4 w0 = {X00, X01, X10, X11};
            u32x4 w1 = {X20, X21, X30, X31};
            pfr[fi][0] = __builtin_bit_cast(bf16x8, w0);
            pfr[fi][1] = __builtin_bit_cast(bf16x8, w1);
        }

        // PV: oacc += V^T x P  (V-frags shared across both fi)
        #pragma unroll
        for (int d = 0; d < 4; ++d) {
            bf16x8 vf0 = __builtin_bit_cast(bf16x8, *(u16x8*)&Vlds[(d * 16 + li) * PAD + g * 8]);
            bf16x8 vf1 = __builtin_bit_cast(bf16x8, *(u16x8*)&Vlds[(d * 16 + li) * PAD + 32 + g * 8]);
            #pragma unroll
            for (int fi = 0; fi < 2; ++fi) {
                if (fi == 0 && !act0) continue;
                oacc[fi][d] = __builtin_amdgcn_mfma_f32_16x16x32_bf16(vf0, pfr[fi][0], oacc[fi][d], 0, 0, 0);
                oacc[fi][d] = __builtin_amdgcn_mfma_f32_16x16x32_bf16(vf1, pfr[fi][1], oacc[fi][d], 0, 0, 0);
            }
        }
    }

    // epilogue: lane owns q-row qf+li, cols dd = d*16 + g*4 + r
    #pragma unroll
    for (int fi = 0; fi < 2; ++fi) {
        const int qf = (fi == 0) ? qrow0 : qrow1;
        const float inv = 1.0f / l_run[fi];
        float* op = Og + ((size_t)(b * SL + qf + li) * NH + h) * HD + g * 4;
        #pragma unroll
        for (int d = 0; d < 4; ++d) {
            f32x4 o = oacc[fi][d];
            #pragma unroll
            for (int r = 0; r < 4; ++r) o[r] *= inv;
            *(f32x4*)(op + d * 16) = o;
        }
    }
}

extern "C" void kernel_launch(void* const* d_in, const int* in_sizes, int n_in,
                              void* d_out, int out_size, void* d_ws, size_t ws_size,
                              hipStream_t stream) {
    const float* Qg = (const float*)d_in[0];
    const float* Kg = (const float*)d_in[1];
    const float* Vg = (const float*)d_in[2];
    float* Og = (float*)d_out;

    const size_t elems = (size_t)NB * NH * SL * HD;
    if (ws_size < 2 * elems * sizeof(unsigned short)) return;
    unsigned short* Kb  = (unsigned short*)d_ws;
    unsigned short* Vtb = Kb + elems;

    hipLaunchKernelGGL(conv_k, dim3(elems / 4 / 256), dim3(256), 0, stream, Kg, Kb);
    hipLaunchKernelGGL(conv_v, dim3(NB * NH * (SL / 64)), dim3(256), 0, stream, Vg, Vtb);
    hipLaunchKernelGGL(fattn_kernel, dim3((NT / 2) * 64), dim3(512), 0, stream,
                       Qg, Kb, Vtb, Og);
}